// Round 8
// baseline (310.144 us; speedup 1.0000x reference)
//
#include <hip/hip_runtime.h>
#include <hip/hip_fp16.h>

// Problem constants (from reference)
constexpr int B = 4, C = 32, H = 544, W = 960;
constexpr int HW = H * W;          // 522240
constexpr int NPIX = B * HW;       // 2088960

// CSR-gather geometry (48x32 tiles, 4ch/pass, 2 blocks/CU, 12 waves/block)
constexpr int TX = 48, TY = 32;            // owned OUTPUT tile
constexpr int PAD = 16;                    // |flow|<=14 provably caught
constexpr int WSX = TX + 2 * PAD;          // 80
constexpr int WSY = TY + 2 * PAD;          // 64
constexpr int WPIX = WSX * WSY;            // 5120
constexpr int TILES_X = W / TX;            // 20 (exact)
constexpr int TILES_Y = H / TY;            // 17 (exact)
constexpr int NTILES = TILES_X * TILES_Y;  // 340
constexpr int TILE = TX * TY;              // 1536
constexpr int TPB = 768;                   // 12 waves
constexpr int NW = TPB / 64;               // 12
constexpr int PPT = TILE / TPB;            // 2 pixels per thread
constexpr int WIT = (WPIX + TPB - 1) / TPB; // 7 window iters (last partial)
constexpr int CAPE = 8448;                 // entry cap (mean ~6.1K, +37%)
constexpr int NCH = 4;                     // channels per pass
constexpr int NPASS = C / NCH;             // 8
constexpr unsigned FARCAP = 32768;

struct FarEntry { unsigned key; float a; int p; };   // key = (b*NTILES+tile)<<11 | lidx

// ---------- pass 0: rare far-flow contributions (|f| > 14) ----------
__global__ __launch_bounds__(256)
void far_scan(const float* __restrict__ flow,
              const float* __restrict__ metric,
              unsigned* __restrict__ counter,
              FarEntry* __restrict__ fl)
{
    int idx = blockIdx.x * blockDim.x + threadIdx.x;
    if (idx >= NPIX) return;
    int b = idx / HW;
    int p = idx - b * HW;
    int y = p / W;
    int x = p - y * W;

    float fx = flow[(size_t)(b * 2 + 0) * HW + p];
    float fy = flow[(size_t)(b * 2 + 1) * HW + p];
    if (fabsf(fx) <= 14.0f && fabsf(fy) <= 14.0f) return;  // in-window guaranteed

    float ox = (float)x + fx, oy = (float)y + fy;
    float x0f = floorf(ox), y0f = floorf(oy);
    int x0 = (int)x0f, y0 = (int)y0f;
    float wxh = ox - x0f, wxl = 1.0f - wxh;
    float wyh = oy - y0f, wyl = 1.0f - wyh;
    const int   cxs[4] = { x0, x0 + 1, x0,     x0 + 1 };
    const int   cys[4] = { y0, y0,     y0 + 1, y0 + 1 };
    const float wts[4] = { wxl * wyl, wxh * wyl, wxl * wyh, wxh * wyh };
    float m = __expf(metric[(size_t)b * HW + p]);

#pragma unroll
    for (int k = 0; k < 4; ++k) {
        int cx = cxs[k], cy = cys[k];
        if ((unsigned)cx >= (unsigned)W || (unsigned)cy >= (unsigned)H) continue;
        int tix = cx / TX, tiy = cy / TY;
        int tx0 = tix * TX, ty0 = tiy * TY;
        bool catchable = (x >= tx0 - PAD) && (x < tx0 + TX + PAD) &&
                         (y >= ty0 - PAD) && (y < ty0 + TY + PAD);
        if (!catchable) {
            unsigned slot = atomicAdd(counter, 1u);
            if (slot < FARCAP) {
                int tile = tiy * TILES_X + tix;
                unsigned lidx = (unsigned)((cy - ty0) * TX + (cx - tx0));
                fl[slot] = { ((unsigned)(b * NTILES + tile) << 11) | lidx,
                             wts[k] * m, p };
            }
        }
    }
}

// ---------- main: per-tile CSR in LDS, balanced gather, 4ch/pass, prefetch ----------
__global__ __launch_bounds__(TPB)
void splat_csr(const float* __restrict__ inp,
               const float* __restrict__ flow,
               const float* __restrict__ metric,
               const unsigned* __restrict__ counter,
               const FarEntry* __restrict__ fl,
               float* __restrict__ out)
{
    __shared__ unsigned entries[CAPE];        // 33792 B : (win_off:u16<<16)|f16(w*m)
    __shared__ unsigned short spix[TILE];     //  3072 B : count-sorted pixel ids
    __shared__ uint2 pool[WPIX];              // 40960 B : cnt+offs, later 4ch window
    __shared__ unsigned hist[33];             //   132 B
    __shared__ unsigned wsum[NW];             //    48 B
    // total ~78.1 KB -> 2 blocks/CU (156 KB <= 160 KB)

    unsigned* cnt  = reinterpret_cast<unsigned*>(pool);   // [1536]
    unsigned* offs = cnt + TILE;                          // [1536]
    uint2*    win  = pool;                                // [5120] after reuse

    const int tile = blockIdx.x;
    const int b    = blockIdx.y;
    const int tx0  = (tile % TILES_X) * TX;
    const int ty0  = (tile / TILES_X) * TY;
    const unsigned btid = (unsigned)(b * NTILES + tile);

    const float* fxp = flow + (size_t)(b * 2 + 0) * HW;
    const float* fyp = flow + (size_t)(b * 2 + 1) * HW;
    const float* mp  = metric + (size_t)b * HW;

    for (int i = threadIdx.x; i < TILE; i += TPB) cnt[i] = 0;
    if (threadIdx.x < 33) hist[threadIdx.x] = 0;
    __syncthreads();

    // ---- count pass ----
#pragma unroll
    for (int j = 0; j < WIT; ++j) {
        int i = threadIdx.x + j * TPB;
        if (i >= WPIX) break;
        int wx = i % WSX, wy = i / WSX;
        int gx = tx0 - PAD + wx, gy = ty0 - PAD + wy;
        if ((unsigned)gx >= (unsigned)W || (unsigned)gy >= (unsigned)H) continue;
        int p = gy * W + gx;
        float ox = (float)gx + fxp[p];
        float oy = (float)gy + fyp[p];
        int lx0 = (int)floorf(ox) - tx0, ly0 = (int)floorf(oy) - ty0;
        if (lx0 < -1 || lx0 >= TX || ly0 < -1 || ly0 >= TY) continue;
#pragma unroll
        for (int k = 0; k < 4; ++k) {
            int lx = lx0 + (k & 1), ly = ly0 + (k >> 1);
            if ((unsigned)lx < (unsigned)TX && (unsigned)ly < (unsigned)TY)
                atomicAdd(&cnt[ly * TX + lx], 1u);
        }
    }
    unsigned farN = *counter;
    if (farN > FARCAP) farN = FARCAP;
    for (unsigned e = threadIdx.x; e < farN; e += TPB) {
        unsigned k = fl[e].key;
        if ((k >> 11) == btid) atomicAdd(&cnt[k & 2047u], 1u);
    }
    __syncthreads();

    // ---- block exclusive prefix-sum over cnt -> offs (2 items/thread) ----
    {
        int t = threadIdx.x;
        unsigned c0 = cnt[2 * t], c1 = cnt[2 * t + 1];
        unsigned s = c0 + c1;
        unsigned lane = t & 63, wv = t >> 6;
        unsigned incl = s;
#pragma unroll
        for (int d = 1; d < 64; d <<= 1) {
            unsigned u = __shfl_up(incl, d);
            if (lane >= (unsigned)d) incl += u;
        }
        if (lane == 63) wsum[wv] = incl;
        __syncthreads();
        if (t < 64) {
            unsigned v = (lane < NW) ? wsum[lane] : 0u;
            unsigned inc2 = v;
#pragma unroll
            for (int d = 1; d < 16; d <<= 1) {
                unsigned u = __shfl_up(inc2, d);
                if (lane >= (unsigned)d) inc2 += u;
            }
            if (lane < NW) wsum[lane] = inc2 - v;   // exclusive wave base
        }
        __syncthreads();
        unsigned base = wsum[wv] + (incl - s);
        offs[2 * t]     = base;
        offs[2 * t + 1] = base + c0;
    }
    __syncthreads();

    // ---- fill pass (same enumeration as count) ----
#pragma unroll
    for (int j = 0; j < WIT; ++j) {
        int i = threadIdx.x + j * TPB;
        if (i >= WPIX) break;
        int wx = i % WSX, wy = i / WSX;
        int gx = tx0 - PAD + wx, gy = ty0 - PAD + wy;
        if ((unsigned)gx >= (unsigned)W || (unsigned)gy >= (unsigned)H) continue;
        int p = gy * W + gx;
        float ox = (float)gx + fxp[p];
        float oy = (float)gy + fyp[p];
        float x0f = floorf(ox), y0f = floorf(oy);
        int lx0 = (int)x0f - tx0, ly0 = (int)y0f - ty0;
        if (lx0 < -1 || lx0 >= TX || ly0 < -1 || ly0 >= TY) continue;
        float wxh = ox - x0f, wxl = 1.0f - wxh;
        float wyh = oy - y0f, wyl = 1.0f - wyh;
        float m = __expf(mp[p]);
        const float w4[4] = { wxl * wyl, wxh * wyl, wxl * wyh, wxh * wyh };
#pragma unroll
        for (int k = 0; k < 4; ++k) {
            int lx = lx0 + (k & 1), ly = ly0 + (k >> 1);
            if ((unsigned)lx < (unsigned)TX && (unsigned)ly < (unsigned)TY) {
                unsigned pos = atomicAdd(&offs[ly * TX + lx], 1u);
                if (pos < CAPE) {
                    unsigned short ha = __half_as_ushort(__float2half(w4[k] * m));
                    entries[pos] = ((unsigned)i << 16) | (unsigned)ha;
                }
            }
        }
    }
    for (unsigned e = threadIdx.x; e < farN; e += TPB) {
        unsigned k = fl[e].key;
        if ((k >> 11) == btid) {
            unsigned pos = atomicAdd(&offs[k & 2047u], 1u);
            if (pos < CAPE) entries[pos] = 0xFFFF0000u | e;   // sentinel: far entry
        }
    }
    __syncthreads();

    // ---- counting sort of owned pixels by entry count (load balance) ----
    for (int i = threadIdx.x; i < TILE; i += TPB)
        atomicAdd(&hist[min(cnt[i], 32u)], 1u);
    __syncthreads();
    if (threadIdx.x == 0) {
        unsigned run = 0;
        for (int i = 0; i < 33; ++i) { unsigned h = hist[i]; hist[i] = run; run += h; }
    }
    __syncthreads();
    for (int i = threadIdx.x; i < TILE; i += TPB) {
        unsigned pos = atomicAdd(&hist[min(cnt[i], 32u)], 1u);
        spix[pos] = (unsigned short)i;
    }
    __syncthreads();

    // ---- per-slot ranges + norm reciprocal (sorted assignment) ----
    int qout[PPT];
    unsigned es[PPT], ee[PPT];
    float rn[PPT];
#pragma unroll
    for (int k = 0; k < PPT; ++k) {
        int sp = spix[threadIdx.x + k * TPB];
        qout[k] = (ty0 + sp / TX) * W + tx0 + (sp % TX);
        unsigned end = offs[sp];
        unsigned start = end - cnt[sp];
        if (end > CAPE) end = CAPE;
        if (start > end) start = end;
        es[k] = start; ee[k] = end;
        float n = 0.0f;
        for (unsigned e = start; e < end; ++e) {
            unsigned ent = entries[e];
            if ((ent >> 16) == 0xFFFFu) n += fl[ent & 0xFFFFu].a;
            else n += __half2float(__ushort_as_half((unsigned short)(ent & 0xFFFFu)));
        }
        rn[k] = (n == 0.0f) ? 1.0f : 1.0f / n;
    }

    // ---- precompute window-pixel global offsets (invariant across passes) ----
    int wp[WIT];
#pragma unroll
    for (int j = 0; j < WIT; ++j) {
        int i = threadIdx.x + j * TPB;
        wp[j] = -1;
        if (i < WPIX) {
            int wx = i % WSX, wy = i / WSX;
            int gx = tx0 - PAD + wx, gy = ty0 - PAD + wy;
            if ((unsigned)gx < (unsigned)W && (unsigned)gy < (unsigned)H)
                wp[j] = gy * W + gx;
        }
    }

    // ---- initial prefetch of channels 0..3 ----
    float4 pre[WIT];
    {
        const float* t0 = inp + (size_t)(b * C) * HW;
#pragma unroll
        for (int j = 0; j < WIT; ++j)
            pre[j] = (wp[j] >= 0)
                   ? make_float4(t0[wp[j]], t0[HW + wp[j]],
                                 t0[2 * HW + wp[j]], t0[3 * HW + wp[j]])
                   : make_float4(0.f, 0.f, 0.f, 0.f);
    }
    __syncthreads();   // cnt/offs dead; pool becomes the window

    // ---- apply: 8 passes x 4 channels, T14 register prefetch ----
    for (int cp = 0; cp < NPASS; ++cp) {
        // stage prefetched quad into LDS
#pragma unroll
        for (int j = 0; j < WIT; ++j) {
            int i = threadIdx.x + j * TPB;
            if (i < WPIX) {
                __half2 h01 = __floats2half2_rn(pre[j].x, pre[j].y);
                __half2 h23 = __floats2half2_rn(pre[j].z, pre[j].w);
                win[i] = make_uint2(*reinterpret_cast<unsigned*>(&h01),
                                    *reinterpret_cast<unsigned*>(&h23));
            }
        }
        __syncthreads();

        // issue next quad's loads early (hidden under the gather)
        if (cp + 1 < NPASS) {
            const float* t0 = inp + (size_t)(b * C + NCH * (cp + 1)) * HW;
#pragma unroll
            for (int j = 0; j < WIT; ++j)
                pre[j] = (wp[j] >= 0)
                       ? make_float4(t0[wp[j]], t0[HW + wp[j]],
                                     t0[2 * HW + wp[j]], t0[3 * HW + wp[j]])
                       : make_float4(0.f, 0.f, 0.f, 0.f);
        }

        const float* s0 = inp + (size_t)(b * C + NCH * cp) * HW;
        float* o0 = out + (size_t)(b * C + NCH * cp) * HW;
#pragma unroll
        for (int k = 0; k < PPT; ++k) {
            float a0 = 0.f, a1 = 0.f, a2 = 0.f, a3 = 0.f;
            for (unsigned e = es[k]; e < ee[k]; ++e) {
                unsigned ent = entries[e];
                unsigned off = ent >> 16;
                if (off == 0xFFFFu) {
                    FarEntry fe = fl[ent & 0xFFFFu];
                    a0 += fe.a * s0[fe.p];
                    a1 += fe.a * s0[HW + fe.p];
                    a2 += fe.a * s0[2 * HW + fe.p];
                    a3 += fe.a * s0[3 * HW + fe.p];
                } else {
                    float a = __half2float(__ushort_as_half((unsigned short)(ent & 0xFFFFu)));
                    uint2 wv = win[off];
                    __half2 h01 = *reinterpret_cast<__half2*>(&wv.x);
                    __half2 h23 = *reinterpret_cast<__half2*>(&wv.y);
                    a0 += a * __low2float(h01);  a1 += a * __high2float(h01);
                    a2 += a * __low2float(h23);  a3 += a * __high2float(h23);
                }
            }
            int q = qout[k];
            o0[q]          = a0 * rn[k];
            o0[HW + q]     = a1 * rn[k];
            o0[2 * HW + q] = a2 * rn[k];
            o0[3 * HW + q] = a3 * rn[k];
        }
        __syncthreads();   // win consumed; safe to overwrite next pass
    }
}

// ---------- fallback path (ws too small): f32 atomics straight into d_out ----------

__global__ __launch_bounds__(256)
void splat_f32(const float* __restrict__ inp,
               const float* __restrict__ flow,
               const float* __restrict__ metric,
               float* __restrict__ out,
               float* __restrict__ norm)
{
    int idx = blockIdx.x * blockDim.x + threadIdx.x;
    if (idx >= NPIX) return;
    int b = idx / HW;
    int p = idx - b * HW;
    int y = p / W;
    int x = p - y * W;

    float fx = flow[(b * 2 + 0) * HW + p];
    float fy = flow[(b * 2 + 1) * HW + p];
    float m  = __expf(metric[b * HW + p]);

    float ox = (float)x + fx, oy = (float)y + fy;
    float x0f = floorf(ox), y0f = floorf(oy);
    int x0 = (int)x0f, y0 = (int)y0f;
    float wx1 = ox - x0f, wx0 = 1.0f - wx1;
    float wy1 = oy - y0f, wy0 = 1.0f - wy1;

    float vm[C];
    const float* inb = inp + (size_t)b * C * HW + p;
#pragma unroll
    for (int c = 0; c < C; ++c) vm[c] = inb[(size_t)c * HW] * m;

    float* outb = out + (size_t)b * C * HW;
    float* nrmb = norm + (size_t)b * HW;

    const int   cxs[4] = { x0, x0 + 1, x0,     x0 + 1 };
    const int   cys[4] = { y0, y0,     y0 + 1, y0 + 1 };
    const float wts[4] = { wx0 * wy0, wx1 * wy0, wx0 * wy1, wx1 * wy1 };

#pragma unroll
    for (int k = 0; k < 4; ++k) {
        int cx = cxs[k], cy = cys[k];
        if (cx < 0 || cx >= W || cy < 0 || cy >= H) continue;
        float wt = wts[k];
        int q = cy * W + cx;
        atomicAdd(&nrmb[q], m * wt);
#pragma unroll
        for (int c = 0; c < C; ++c)
            atomicAdd(&outb[(size_t)c * HW + q], vm[c] * wt);
    }
}

__global__ __launch_bounds__(256)
void normalize_f32(float* __restrict__ out, const float* __restrict__ norm)
{
    int t = blockIdx.x * blockDim.x + threadIdx.x;
    long long base = (long long)t * 4;
    if (base >= (long long)B * C * HW) return;
    long long b = base / ((long long)C * HW);
    long long q = base % HW;

    float4 o = *reinterpret_cast<float4*>(out + base);
    float4 n = *reinterpret_cast<const float4*>(norm + b * HW + q);
    o.x /= (n.x == 0.0f ? 1.0f : n.x);
    o.y /= (n.y == 0.0f ? 1.0f : n.y);
    o.z /= (n.z == 0.0f ? 1.0f : n.z);
    o.w /= (n.w == 0.0f ? 1.0f : n.w);
    *reinterpret_cast<float4*>(out + base) = o;
}

extern "C" void kernel_launch(void* const* d_in, const int* in_sizes, int n_in,
                              void* d_out, int out_size, void* d_ws, size_t ws_size,
                              hipStream_t stream) {
    const float* tenInput  = (const float*)d_in[0];
    const float* tenFlow   = (const float*)d_in[1];
    const float* tenMetric = (const float*)d_in[2];
    float* out = (float*)d_out;

    const size_t need = 16 + (size_t)FARCAP * sizeof(FarEntry);   // ~384 KB

    if (ws_size >= need) {
        unsigned* counter = (unsigned*)d_ws;
        FarEntry* fl = (FarEntry*)((char*)d_ws + 16);

        hipMemsetAsync(counter, 0, 16, stream);
        far_scan<<<(NPIX + 255) / 256, 256, 0, stream>>>(tenFlow, tenMetric, counter, fl);

        dim3 grid(NTILES, B);
        splat_csr<<<grid, TPB, 0, stream>>>(tenInput, tenFlow, tenMetric,
                                            counter, fl, out);
    } else {
        float* norm = (float*)d_ws;
        hipMemsetAsync(out, 0, (size_t)B * C * HW * sizeof(float), stream);
        hipMemsetAsync(norm, 0, (size_t)NPIX * sizeof(float), stream);

        int threads = 256;
        int blocks = (NPIX + threads - 1) / threads;
        splat_f32<<<blocks, threads, 0, stream>>>(tenInput, tenFlow, tenMetric, out, norm);

        long long total = (long long)B * C * HW / 4;
        normalize_f32<<<(int)((total + threads - 1) / threads), threads, 0, stream>>>(out, norm);
    }
}

// Round 9
// 271.948 us; speedup vs baseline: 1.1405x; 1.1405x over previous
//
#include <hip/hip_runtime.h>
#include <hip/hip_fp16.h>

// Problem constants (from reference)
constexpr int B = 4, C = 32, H = 544, W = 960;
constexpr int HW = H * W;          // 522240
constexpr int NPIX = B * HW;       // 2088960

// CSR-gather geometry (64x32 tiles, 2ch/pass, 2 blocks/CU, 16 waves/block)
constexpr int TX = 64, TY = 32;            // owned OUTPUT tile
constexpr int PAD = 16;                    // |flow|<=14 provably caught
constexpr int WSX = TX + 2 * PAD;          // 96
constexpr int WSY = TY + 2 * PAD;          // 64
constexpr int WPIX = WSX * WSY;            // 6144
constexpr int TILES_X = W / TX;            // 15 (exact)
constexpr int TILES_Y = H / TY;            // 17 (exact)
constexpr int NTILES = TILES_X * TILES_Y;  // 255
constexpr int TILE = TX * TY;              // 2048
constexpr int TPB = 1024;                  // 16 waves
constexpr int NW = TPB / 64;               // 16
constexpr int PPT = TILE / TPB;            // 2 pixels per thread
constexpr int WIT = WPIX / TPB;            // 6 window iters (exact)
constexpr int CAPE = 11264;                // entry cap (mean ~8.2K, +37%)
constexpr unsigned FARCAP = 32768;

struct FarEntry { unsigned key; float a; int p; };   // key = (b*NTILES+tile)<<11 | lidx

// ---------- pass 0: rare far-flow contributions (|f| > 14) ----------
__global__ __launch_bounds__(256)
void far_scan(const float* __restrict__ flow,
              const float* __restrict__ metric,
              unsigned* __restrict__ counter,
              FarEntry* __restrict__ fl)
{
    int idx = blockIdx.x * blockDim.x + threadIdx.x;
    if (idx >= NPIX) return;
    int b = idx / HW;
    int p = idx - b * HW;
    int y = p / W;
    int x = p - y * W;

    float fx = flow[(size_t)(b * 2 + 0) * HW + p];
    float fy = flow[(size_t)(b * 2 + 1) * HW + p];
    if (fabsf(fx) <= 14.0f && fabsf(fy) <= 14.0f) return;  // in-window guaranteed

    float ox = (float)x + fx, oy = (float)y + fy;
    float x0f = floorf(ox), y0f = floorf(oy);
    int x0 = (int)x0f, y0 = (int)y0f;
    float wxh = ox - x0f, wxl = 1.0f - wxh;
    float wyh = oy - y0f, wyl = 1.0f - wyh;
    const int   cxs[4] = { x0, x0 + 1, x0,     x0 + 1 };
    const int   cys[4] = { y0, y0,     y0 + 1, y0 + 1 };
    const float wts[4] = { wxl * wyl, wxh * wyl, wxl * wyh, wxh * wyh };
    float m = __expf(metric[(size_t)b * HW + p]);

#pragma unroll
    for (int k = 0; k < 4; ++k) {
        int cx = cxs[k], cy = cys[k];
        if ((unsigned)cx >= (unsigned)W || (unsigned)cy >= (unsigned)H) continue;
        int tx0 = (cx >> 6) << 6;
        int ty0 = (cy >> 5) << 5;
        bool catchable = (x >= tx0 - PAD) && (x < tx0 + TX + PAD) &&
                         (y >= ty0 - PAD) && (y < ty0 + TY + PAD);
        if (!catchable) {
            unsigned slot = atomicAdd(counter, 1u);
            if (slot < FARCAP) {
                int tile = (cy >> 5) * TILES_X + (cx >> 6);
                unsigned lidx = (unsigned)(((cy - ty0) << 6) | (cx - tx0));
                fl[slot] = { ((unsigned)(b * NTILES + tile) << 11) | lidx,
                             wts[k] * m, p };
            }
        }
    }
}

// ---------- main: per-tile CSR in LDS, balanced gather, T14 prefetch ----------
__global__ __launch_bounds__(TPB)
void splat_csr(const float* __restrict__ inp,
               const float* __restrict__ flow,
               const float* __restrict__ metric,
               const unsigned* __restrict__ counter,
               const FarEntry* __restrict__ fl,
               float* __restrict__ out)
{
    __shared__ unsigned entries[CAPE];        // 45056 B : (win_off:u16<<16)|f16(w*m)
    __shared__ unsigned short spix[TILE];     //  4096 B : count-sorted pixel ids
    __shared__ unsigned pool[WPIX];           // 24576 B : offs[2048], later 2ch window
    __shared__ unsigned hist[33];             //   132 B
    __shared__ unsigned wsum[NW];             //    64 B
    // total ~73.9 KB -> 2 blocks/CU -> 32 waves/CU

    unsigned* offs = pool;                                   // [2048]
    __half2*  win  = reinterpret_cast<__half2*>(pool);       // [6144] after reuse

    const int tile = blockIdx.x;
    const int b    = blockIdx.y;
    const int tx0  = (tile % TILES_X) * TX;
    const int ty0  = (tile / TILES_X) * TY;
    const unsigned btid = (unsigned)(b * NTILES + tile);

    const float* fxp = flow + (size_t)(b * 2 + 0) * HW;
    const float* fyp = flow + (size_t)(b * 2 + 1) * HW;
    const float* mp  = metric + (size_t)b * HW;

    for (int i = threadIdx.x; i < TILE; i += TPB) offs[i] = 0;
    if (threadIdx.x < 33) hist[threadIdx.x] = 0;
    __syncthreads();

    // ---- count pass (into offs) ----
#pragma unroll
    for (int j = 0; j < WIT; ++j) {
        int i = threadIdx.x + j * TPB;
        int wx = i % WSX, wy = i / WSX;
        int gx = tx0 - PAD + wx, gy = ty0 - PAD + wy;
        if ((unsigned)gx >= (unsigned)W || (unsigned)gy >= (unsigned)H) continue;
        int p = gy * W + gx;
        float ox = (float)gx + fxp[p];
        float oy = (float)gy + fyp[p];
        int lx0 = (int)floorf(ox) - tx0, ly0 = (int)floorf(oy) - ty0;
        if (lx0 < -1 || lx0 >= TX || ly0 < -1 || ly0 >= TY) continue;
#pragma unroll
        for (int k = 0; k < 4; ++k) {
            int lx = lx0 + (k & 1), ly = ly0 + (k >> 1);
            if ((unsigned)lx < (unsigned)TX && (unsigned)ly < (unsigned)TY)
                atomicAdd(&offs[(ly << 6) + lx], 1u);
        }
    }
    unsigned farN = *counter;
    if (farN > FARCAP) farN = FARCAP;
    for (unsigned e = threadIdx.x; e < farN; e += TPB) {
        unsigned k = fl[e].key;
        if ((k >> 11) == btid) atomicAdd(&offs[k & 2047u], 1u);
    }
    __syncthreads();

    // ---- block exclusive prefix-sum over offs, in place (2 items/thread) ----
    {
        int t = threadIdx.x;
        unsigned c0 = offs[2 * t], c1 = offs[2 * t + 1];
        unsigned s = c0 + c1;
        unsigned lane = t & 63, wv = t >> 6;
        unsigned incl = s;
#pragma unroll
        for (int d = 1; d < 64; d <<= 1) {
            unsigned u = __shfl_up(incl, d);
            if (lane >= (unsigned)d) incl += u;
        }
        if (lane == 63) wsum[wv] = incl;
        __syncthreads();
        if (t < 64) {
            unsigned v = (lane < NW) ? wsum[lane] : 0u;
            unsigned inc2 = v;
#pragma unroll
            for (int d = 1; d < 16; d <<= 1) {
                unsigned u = __shfl_up(inc2, d);
                if (lane >= (unsigned)d) inc2 += u;
            }
            if (lane < NW) wsum[lane] = inc2 - v;   // exclusive wave base
        }
        __syncthreads();
        unsigned base = wsum[wv] + (incl - s);
        offs[2 * t]     = base;
        offs[2 * t + 1] = base + c0;
    }
    __syncthreads();

    // ---- fill pass (offs[i] becomes range END afterwards) ----
#pragma unroll
    for (int j = 0; j < WIT; ++j) {
        int i = threadIdx.x + j * TPB;
        int wx = i % WSX, wy = i / WSX;
        int gx = tx0 - PAD + wx, gy = ty0 - PAD + wy;
        if ((unsigned)gx >= (unsigned)W || (unsigned)gy >= (unsigned)H) continue;
        int p = gy * W + gx;
        float ox = (float)gx + fxp[p];
        float oy = (float)gy + fyp[p];
        float x0f = floorf(ox), y0f = floorf(oy);
        int lx0 = (int)x0f - tx0, ly0 = (int)y0f - ty0;
        if (lx0 < -1 || lx0 >= TX || ly0 < -1 || ly0 >= TY) continue;
        float wxh = ox - x0f, wxl = 1.0f - wxh;
        float wyh = oy - y0f, wyl = 1.0f - wyh;
        float m = __expf(mp[p]);
        const float w4[4] = { wxl * wyl, wxh * wyl, wxl * wyh, wxh * wyh };
#pragma unroll
        for (int k = 0; k < 4; ++k) {
            int lx = lx0 + (k & 1), ly = ly0 + (k >> 1);
            if ((unsigned)lx < (unsigned)TX && (unsigned)ly < (unsigned)TY) {
                unsigned pos = atomicAdd(&offs[(ly << 6) + lx], 1u);
                if (pos < CAPE) {
                    unsigned short ha = __half_as_ushort(__float2half(w4[k] * m));
                    entries[pos] = ((unsigned)i << 16) | (unsigned)ha;
                }
            }
        }
    }
    for (unsigned e = threadIdx.x; e < farN; e += TPB) {
        unsigned k = fl[e].key;
        if ((k >> 11) == btid) {
            unsigned pos = atomicAdd(&offs[k & 2047u], 1u);
            if (pos < CAPE) entries[pos] = 0xFFFF0000u | e;   // sentinel: far entry
        }
    }
    __syncthreads();

    // ---- counting sort of owned pixels by entry count (load balance) ----
    for (int i = threadIdx.x; i < TILE; i += TPB) {
        unsigned end = min(offs[i], (unsigned)CAPE);
        unsigned start = min(i ? offs[i - 1] : 0u, (unsigned)CAPE);
        unsigned c = end > start ? end - start : 0u;
        atomicAdd(&hist[min(c, 32u)], 1u);
    }
    __syncthreads();
    if (threadIdx.x == 0) {
        unsigned run = 0;
        for (int i = 0; i < 33; ++i) { unsigned h = hist[i]; hist[i] = run; run += h; }
    }
    __syncthreads();
    for (int i = threadIdx.x; i < TILE; i += TPB) {
        unsigned end = min(offs[i], (unsigned)CAPE);
        unsigned start = min(i ? offs[i - 1] : 0u, (unsigned)CAPE);
        unsigned c = end > start ? end - start : 0u;
        unsigned pos = atomicAdd(&hist[min(c, 32u)], 1u);
        spix[pos] = (unsigned short)i;
    }
    __syncthreads();

    // ---- per-slot ranges + norm reciprocal (sorted assignment) ----
    int qout[PPT];
    unsigned es[PPT], ee[PPT];
    float rn[PPT];
#pragma unroll
    for (int k = 0; k < PPT; ++k) {
        int sp = spix[threadIdx.x + k * TPB];
        qout[k] = (ty0 + (sp >> 6)) * W + tx0 + (sp & 63);
        unsigned end = min(offs[sp], (unsigned)CAPE);
        unsigned start = min(sp ? offs[sp - 1] : 0u, (unsigned)CAPE);
        if (start > end) start = end;
        es[k] = start; ee[k] = end;
        float n = 0.0f;
        for (unsigned e = start; e < end; ++e) {
            unsigned ent = entries[e];
            if ((ent >> 16) == 0xFFFFu) n += fl[ent & 0xFFFFu].a;
            else n += __half2float(__ushort_as_half((unsigned short)(ent & 0xFFFFu)));
        }
        rn[k] = (n == 0.0f) ? 1.0f : 1.0f / n;
    }

    // ---- precompute window-pixel global offsets (invariant across passes) ----
    int wp[WIT];
#pragma unroll
    for (int j = 0; j < WIT; ++j) {
        int i = threadIdx.x + j * TPB;
        int wx = i % WSX, wy = i / WSX;
        int gx = tx0 - PAD + wx, gy = ty0 - PAD + wy;
        wp[j] = ((unsigned)gx < (unsigned)W && (unsigned)gy < (unsigned)H)
                ? gy * W + gx : -1;
    }

    // ---- initial prefetch of channels 0..1 ----
    float2 pre[WIT];
    {
        const float* t0 = inp + (size_t)(b * C) * HW;
        const float* t1 = t0 + HW;
#pragma unroll
        for (int j = 0; j < WIT; ++j)
            pre[j] = (wp[j] >= 0) ? make_float2(t0[wp[j]], t1[wp[j]])
                                  : make_float2(0.f, 0.f);
    }
    __syncthreads();   // offs dead; pool becomes the window

    // ---- apply: 16 passes x 2 channels, T14 register prefetch ----
    for (int cp = 0; cp < C / 2; ++cp) {
        // stage prefetched pair into LDS
#pragma unroll
        for (int j = 0; j < WIT; ++j)
            win[threadIdx.x + j * TPB] = __floats2half2_rn(pre[j].x, pre[j].y);
        __syncthreads();

        // issue next pair's loads early (hidden under the gather)
        if (cp + 1 < C / 2) {
            const float* t0 = inp + (size_t)(b * C + 2 * (cp + 1)) * HW;
            const float* t1 = t0 + HW;
#pragma unroll
            for (int j = 0; j < WIT; ++j)
                pre[j] = (wp[j] >= 0) ? make_float2(t0[wp[j]], t1[wp[j]])
                                      : make_float2(0.f, 0.f);
        }

        const float* s0 = inp + (size_t)(b * C + 2 * cp) * HW;
        const float* s1 = s0 + HW;
        float* o0 = out + (size_t)(b * C + 2 * cp) * HW;
        float* o1 = o0 + HW;
#pragma unroll
        for (int k = 0; k < PPT; ++k) {
            float a0 = 0.f, a1 = 0.f;
            for (unsigned e = es[k]; e < ee[k]; ++e) {
                unsigned ent = entries[e];
                unsigned off = ent >> 16;
                if (off == 0xFFFFu) {
                    FarEntry fe = fl[ent & 0xFFFFu];
                    a0 += fe.a * s0[fe.p]; a1 += fe.a * s1[fe.p];
                } else {
                    float a = __half2float(__ushort_as_half((unsigned short)(ent & 0xFFFFu)));
                    __half2 hv = win[off];
                    a0 += a * __low2float(hv); a1 += a * __high2float(hv);
                }
            }
            int q = qout[k];
            o0[q] = a0 * rn[k];
            o1[q] = a1 * rn[k];
        }
        __syncthreads();   // win consumed; safe to overwrite next pass
    }
}

// ---------- fallback path (ws too small): f32 atomics straight into d_out ----------

__global__ __launch_bounds__(256)
void splat_f32(const float* __restrict__ inp,
               const float* __restrict__ flow,
               const float* __restrict__ metric,
               float* __restrict__ out,
               float* __restrict__ norm)
{
    int idx = blockIdx.x * blockDim.x + threadIdx.x;
    if (idx >= NPIX) return;
    int b = idx / HW;
    int p = idx - b * HW;
    int y = p / W;
    int x = p - y * W;

    float fx = flow[(b * 2 + 0) * HW + p];
    float fy = flow[(b * 2 + 1) * HW + p];
    float m  = __expf(metric[b * HW + p]);

    float ox = (float)x + fx, oy = (float)y + fy;
    float x0f = floorf(ox), y0f = floorf(oy);
    int x0 = (int)x0f, y0 = (int)y0f;
    float wx1 = ox - x0f, wx0 = 1.0f - wx1;
    float wy1 = oy - y0f, wy0 = 1.0f - wy1;

    float vm[C];
    const float* inb = inp + (size_t)b * C * HW + p;
#pragma unroll
    for (int c = 0; c < C; ++c) vm[c] = inb[(size_t)c * HW] * m;

    float* outb = out + (size_t)b * C * HW;
    float* nrmb = norm + (size_t)b * HW;

    const int   cxs[4] = { x0, x0 + 1, x0,     x0 + 1 };
    const int   cys[4] = { y0, y0,     y0 + 1, y0 + 1 };
    const float wts[4] = { wx0 * wy0, wx1 * wy0, wx0 * wy1, wx1 * wy1 };

#pragma unroll
    for (int k = 0; k < 4; ++k) {
        int cx = cxs[k], cy = cys[k];
        if (cx < 0 || cx >= W || cy < 0 || cy >= H) continue;
        float wt = wts[k];
        int q = cy * W + cx;
        atomicAdd(&nrmb[q], m * wt);
#pragma unroll
        for (int c = 0; c < C; ++c)
            atomicAdd(&outb[(size_t)c * HW + q], vm[c] * wt);
    }
}

__global__ __launch_bounds__(256)
void normalize_f32(float* __restrict__ out, const float* __restrict__ norm)
{
    int t = blockIdx.x * blockDim.x + threadIdx.x;
    long long base = (long long)t * 4;
    if (base >= (long long)B * C * HW) return;
    long long b = base / ((long long)C * HW);
    long long q = base % HW;

    float4 o = *reinterpret_cast<float4*>(out + base);
    float4 n = *reinterpret_cast<const float4*>(norm + b * HW + q);
    o.x /= (n.x == 0.0f ? 1.0f : n.x);
    o.y /= (n.y == 0.0f ? 1.0f : n.y);
    o.z /= (n.z == 0.0f ? 1.0f : n.z);
    o.w /= (n.w == 0.0f ? 1.0f : n.w);
    *reinterpret_cast<float4*>(out + base) = o;
}

extern "C" void kernel_launch(void* const* d_in, const int* in_sizes, int n_in,
                              void* d_out, int out_size, void* d_ws, size_t ws_size,
                              hipStream_t stream) {
    const float* tenInput  = (const float*)d_in[0];
    const float* tenFlow   = (const float*)d_in[1];
    const float* tenMetric = (const float*)d_in[2];
    float* out = (float*)d_out;

    const size_t need = 16 + (size_t)FARCAP * sizeof(FarEntry);   // ~384 KB

    if (ws_size >= need) {
        unsigned* counter = (unsigned*)d_ws;
        FarEntry* fl = (FarEntry*)((char*)d_ws + 16);

        hipMemsetAsync(counter, 0, 16, stream);
        far_scan<<<(NPIX + 255) / 256, 256, 0, stream>>>(tenFlow, tenMetric, counter, fl);

        dim3 grid(NTILES, B);
        splat_csr<<<grid, TPB, 0, stream>>>(tenInput, tenFlow, tenMetric,
                                            counter, fl, out);
    } else {
        float* norm = (float*)d_ws;
        hipMemsetAsync(out, 0, (size_t)B * C * HW * sizeof(float), stream);
        hipMemsetAsync(norm, 0, (size_t)NPIX * sizeof(float), stream);

        int threads = 256;
        int blocks = (NPIX + threads - 1) / threads;
        splat_f32<<<blocks, threads, 0, stream>>>(tenInput, tenFlow, tenMetric, out, norm);

        long long total = (long long)B * C * HW / 4;
        normalize_f32<<<(int)((total + threads - 1) / threads), threads, 0, stream>>>(out, norm);
    }
}